// Round 16
// baseline (405.508 us; speedup 1.0000x reference)
//
#include <hip/hip_runtime.h>
#include <math.h>

#define HW 16384

typedef float f32x4 __attribute__((ext_vector_type(4)));
typedef __bf16 bf16x8 __attribute__((ext_vector_type(8)));
typedef unsigned short u16x4 __attribute__((ext_vector_type(4)));
typedef unsigned short u16x8 __attribute__((ext_vector_type(8)));

__device__ __forceinline__ unsigned short f2bf(float f) {
  unsigned u = __float_as_uint(f);
  u += 0x7fffu + ((u >> 16) & 1u);
  return (unsigned short)(u >> 16);
}
__device__ __forceinline__ float bf2f(unsigned short s) {
  return __uint_as_float(((unsigned)s) << 16);
}

// ---------------------------------------------------------------------------
// prep: w1,w2,w3 fp32 -> bf16; wr[br][tap][kt(16,pad)][c(128)] from (9,128,3,3)
// ---------------------------------------------------------------------------
__global__ void prep_kernel(const float* __restrict__ w1, const float* __restrict__ w2,
                            const float* __restrict__ w3,
                            const float* __restrict__ wa, const float* __restrict__ wb,
                            const float* __restrict__ wc, const float* __restrict__ wd,
                            unsigned short* __restrict__ w1b, unsigned short* __restrict__ w2b,
                            unsigned short* __restrict__ w3b, unsigned short* __restrict__ wr) {
  int idx = blockIdx.x * 256 + threadIdx.x;
  if (idx < 65536) { w1b[idx] = f2bf(w1[idx]); }
  else if (idx < 147456) { int j = idx - 65536; w2b[j] = f2bf(w2[j]); }
  else if (idx < 212992) { int j = idx - 147456; w3b[j] = f2bf(w3[j]); }
  else if (idx < 286720) {
    int j = idx - 212992;
    int br = j / 18432, rem = j % 18432;
    int tap = rem / 2048, rem2 = rem % 2048;
    int kt = rem2 / 128, c = rem2 % 128;
    const float* w = (br == 0) ? wa : (br == 1) ? wb : (br == 2) ? wc : wd;
    float v = (kt < 9) ? w[(kt * 128 + c) * 9 + tap] : 0.f;
    wr[j] = f2bf(v);
  }
}

// ---------------------------------------------------------------------------
// GN partial-stats epilogue helper.
// part layout: [((n*32+g)*256 + blkx)*2 + {0,1}]
// ---------------------------------------------------------------------------
__device__ __forceinline__ void gn_partial_epilogue(
    f32x4 (&acc)[8], int wv, int lane, int t, int n, int blkx,
    float* __restrict__ part, float (*ps)[32], float (*pss)[32]) {
  float gs[8], gss[8];
#pragma unroll
  for (int cb = 0; cb < 8; ++cb) {
    float s = 0.f, ss = 0.f;
#pragma unroll
    for (int r = 0; r < 4; ++r) { float v = acc[cb][r]; s += v; ss += v * v; }
#pragma unroll
    for (int m = 0; m < 4; ++m) {
      const int msk[4] = {1, 2, 16, 32};
      s += __shfl_xor(s, msk[m]); ss += __shfl_xor(ss, msk[m]);
    }
    gs[cb] = s; gss[cb] = ss;
  }
  if (lane < 16 && (lane & 3) == 0) {
    int q = lane >> 2;
#pragma unroll
    for (int cb = 0; cb < 8; ++cb) { ps[wv][cb * 4 + q] = gs[cb]; pss[wv][cb * 4 + q] = gss[cb]; }
  }
  __syncthreads();
  if (t < 32) {
    float a = ps[0][t] + ps[1][t] + ps[2][t] + ps[3][t];
    float b = pss[0][t] + pss[1][t] + pss[2][t] + pss[3][t];
    float* pp = part + ((size_t)(n * 32 + t) * 256 + blkx) * 2;
    pp[0] = a; pp[1] = b;
  }
}

// ---------------------------------------------------------------------------
// conv1f (R11): fused transpose + 1x1 conv 512->128, dbuf staging,
// LDS [ch][px] (+1 pad). Raw bf16 out (cat cols 0..127) + fused GN1 partials.
// ---------------------------------------------------------------------------
__global__ __launch_bounds__(256) void conv1f_kernel(
    const float* __restrict__ x, const unsigned short* __restrict__ w1b,
    unsigned short* __restrict__ outb, float* __restrict__ part) {
  __shared__ float xs[2][64][65];
  __shared__ float ps[4][32], pss[4][32];
  int t = threadIdx.x;
  int wv = t >> 6, lane = t & 63, lr = lane & 15, lg = lane >> 4;
  int n = blockIdx.y;
  int p0 = blockIdx.x * 64;
  const float* xn = x + (size_t)n * 512 * HW + p0;
  f32x4 acc[8];
#pragma unroll
  for (int cb = 0; cb < 8; ++cb) acc[cb] = (f32x4){0.f, 0.f, 0.f, 0.f};

  int ci_l = t >> 4, px4 = (t & 15) * 4;
  float4 r[4];

#pragma unroll
  for (int pass = 0; pass < 4; ++pass)
    r[pass] = *(const float4*)(xn + (size_t)(pass * 16 + ci_l) * HW + px4);
#pragma unroll
  for (int pass = 0; pass < 4; ++pass) {
    int cl = pass * 16 + ci_l;
    xs[0][cl][px4 + 0] = r[pass].x; xs[0][cl][px4 + 1] = r[pass].y;
    xs[0][cl][px4 + 2] = r[pass].z; xs[0][cl][px4 + 3] = r[pass].w;
  }

  for (int kt = 0; kt < 8; ++kt) {
    int cur = kt & 1;
    if (kt < 7) {
#pragma unroll
      for (int pass = 0; pass < 4; ++pass)
        r[pass] = *(const float4*)(xn + (size_t)((kt + 1) * 64 + pass * 16 + ci_l) * HW + px4);
    }
    __syncthreads();
#pragma unroll
    for (int ks = 0; ks < 2; ++ks) {
      bf16x8 a;
#pragma unroll
      for (int j = 0; j < 8; ++j) {
        unsigned short us = f2bf(xs[cur][ks * 32 + lg * 8 + j][wv * 16 + lr]);
        a[j] = *(__bf16*)&us;
      }
#pragma unroll
      for (int cb = 0; cb < 8; ++cb) {
        bf16x8 b = *(const bf16x8*)(w1b + (size_t)(cb * 16 + lr) * 512
                                    + kt * 64 + ks * 32 + lg * 8);
        acc[cb] = __builtin_amdgcn_mfma_f32_16x16x32_bf16(a, b, acc[cb], 0, 0, 0);
      }
    }
    if (kt < 7) {
#pragma unroll
      for (int pass = 0; pass < 4; ++pass) {
        int cl = pass * 16 + ci_l;
        xs[cur ^ 1][cl][px4 + 0] = r[pass].x; xs[cur ^ 1][cl][px4 + 1] = r[pass].y;
        xs[cur ^ 1][cl][px4 + 2] = r[pass].z; xs[cur ^ 1][cl][px4 + 3] = r[pass].w;
      }
    }
  }
  unsigned short* on = outb + (size_t)n * HW * 640;
#pragma unroll
  for (int cb = 0; cb < 8; ++cb)
#pragma unroll
    for (int r2 = 0; r2 < 4; ++r2)
      on[(size_t)(p0 + wv * 16 + lg * 4 + r2) * 640 + cb * 16 + lr] = f2bf(acc[cb][r2]);
  __syncthreads();
  gn_partial_epilogue(acc, wv, lane, t, n, blockIdx.x, part, ps, pss);
}

// ---------------------------------------------------------------------------
// conv2 MFMA (R11), 64-px blocks, raw bf16 out + fused GN2 partials
// ---------------------------------------------------------------------------
template<int K>
__global__ __launch_bounds__(256) void conv_pm_kernel(
    const unsigned short* __restrict__ act, const unsigned short* __restrict__ w,
    unsigned short* __restrict__ outb, float* __restrict__ part, int ldd) {
  __shared__ float ps[4][32], pss[4][32];
  int t = threadIdx.x;
  int wv = t >> 6, lane = t & 63;
  int lr = lane & 15, lg = lane >> 4;
  int n = blockIdx.y;
  int p0 = blockIdx.x * 64 + wv * 16;
  const unsigned short* an = act + (size_t)n * HW * K;
  f32x4 acc[8];
#pragma unroll
  for (int cb = 0; cb < 8; ++cb) acc[cb] = (f32x4){0.f, 0.f, 0.f, 0.f};
  const unsigned short* ap = an + (size_t)(p0 + lr) * K + lg * 8;
  const unsigned short* bp = w + (size_t)lr * K + lg * 8;
  for (int ks = 0; ks < K / 32; ++ks) {
    bf16x8 a = *(const bf16x8*)(ap + ks * 32);
#pragma unroll
    for (int cb = 0; cb < 8; ++cb) {
      bf16x8 b = *(const bf16x8*)(bp + (size_t)cb * 16 * K + ks * 32);
      acc[cb] = __builtin_amdgcn_mfma_f32_16x16x32_bf16(a, b, acc[cb], 0, 0, 0);
    }
  }
  unsigned short* on = outb + (size_t)n * HW * ldd;
#pragma unroll
  for (int cb = 0; cb < 8; ++cb)
#pragma unroll
    for (int r = 0; r < 4; ++r)
      on[(size_t)(p0 + lg * 4 + r) * ldd + cb * 16 + lr] = f2bf(acc[cb][r]);
  gn_partial_epilogue(acc, wv, lane, t, n, blockIdx.x, part, ps, pss);
}

// gnf256 wide: 1024 threads, 8-way split per (n,g); count = 4ch*HW
__global__ __launch_bounds__(1024) void gnf256_kernel(
    const float* __restrict__ part, float* __restrict__ stats) {
  __shared__ float sh[1024], sh2[1024];
  int t = threadIdx.x;
  int tg = t >> 3, sub = t & 7;
  float s = 0.f, ss = 0.f;
  for (int b = sub * 32; b < sub * 32 + 32; ++b) {
    const float* pp = part + ((size_t)tg * 256 + b) * 2;
    s += pp[0]; ss += pp[1];
  }
  sh[t] = s; sh2[t] = ss;
  __syncthreads();
  if (t < 128) {
    float a = 0.f, b2 = 0.f;
#pragma unroll
    for (int i = 0; i < 8; ++i) { a += sh[t * 8 + i]; b2 += sh2[t * 8 + i]; }
    float inv = 1.f / (4.f * HW);
    float mean = a * inv, var = b2 * inv - mean * mean;
    stats[2 * t] = mean; stats[2 * t + 1] = rsqrtf(var + 1e-5f);
  }
}

// GN apply IN PLACE on bf16 buffer (+ReLU), row stride ldd
__global__ __launch_bounds__(256) void gna_ip_kernel(
    unsigned short* __restrict__ dst, const float* __restrict__ stats,
    const float* __restrict__ gamma, const float* __restrict__ beta, int ldd) {
  int idx = blockIdx.x * 256 + threadIdx.x;
  int g = idx & 31;
  int p = (idx >> 5) & (HW - 1);
  int n = idx >> 19;
  unsigned short* ptr = dst + ((size_t)n * HW + p) * ldd + 4 * g;
  u16x4 v = *(u16x4*)ptr;
  int sg = n * 32 + g;
  float mean = stats[2 * sg], rstd = stats[2 * sg + 1];
  float sc0 = rstd * gamma[4 * g + 0], sc1 = rstd * gamma[4 * g + 1];
  float sc2 = rstd * gamma[4 * g + 2], sc3 = rstd * gamma[4 * g + 3];
  float sh0 = beta[4 * g + 0] - mean * sc0, sh1 = beta[4 * g + 1] - mean * sc1;
  float sh2 = beta[4 * g + 2] - mean * sc2, sh3 = beta[4 * g + 3] - mean * sc3;
  u16x4 o;
  o[0] = f2bf(fmaxf(fmaf(bf2f(v[0]), sc0, sh0), 0.f));
  o[1] = f2bf(fmaxf(fmaf(bf2f(v[1]), sc1, sh1), 0.f));
  o[2] = f2bf(fmaxf(fmaf(bf2f(v[2]), sc2, sh2), 0.f));
  o[3] = f2bf(fmaxf(fmaf(bf2f(v[3]), sc3, sh3), 0.f));
  *(u16x4*)ptr = o;
}

// ---------------------------------------------------------------------------
// conv3 MFMA (R11 one-pass) -> y3b bf16 channel-major + fused GN3 partials
// ---------------------------------------------------------------------------
__global__ __launch_bounds__(256) void conv3_kernel(
    const unsigned short* __restrict__ y, const unsigned short* __restrict__ w3,
    unsigned short* __restrict__ outb, float* __restrict__ part) {
  int wv = threadIdx.x >> 6, lane = threadIdx.x & 63;
  int lr = lane & 15, lg = lane >> 4;
  int n = blockIdx.y, zc = blockIdx.z;
  int co0 = zc * 128 + wv * 32;
  int p0 = blockIdx.x * 128;
  const unsigned short* yn = y + (size_t)n * HW * 128;
  f32x4 acc[2][8];
#pragma unroll
  for (int pr = 0; pr < 2; ++pr)
#pragma unroll
    for (int cb = 0; cb < 8; ++cb) acc[pr][cb] = (f32x4){0.f, 0.f, 0.f, 0.f};
#pragma unroll
  for (int ks = 0; ks < 4; ++ks) {
    bf16x8 a0 = *(const bf16x8*)(w3 + (size_t)(co0 + lr) * 128 + ks * 32 + lg * 8);
    bf16x8 a1 = *(const bf16x8*)(w3 + (size_t)(co0 + 16 + lr) * 128 + ks * 32 + lg * 8);
#pragma unroll
    for (int cb = 0; cb < 8; ++cb) {
      bf16x8 b = *(const bf16x8*)(yn + (size_t)(p0 + cb * 16 + lr) * 128 + ks * 32 + lg * 8);
      acc[0][cb] = __builtin_amdgcn_mfma_f32_16x16x32_bf16(a0, b, acc[0][cb], 0, 0, 0);
      acc[1][cb] = __builtin_amdgcn_mfma_f32_16x16x32_bf16(a1, b, acc[1][cb], 0, 0, 0);
    }
  }
  unsigned short* on = outb + (size_t)n * 512 * HW;
  float s[2] = {0.f, 0.f}, ss[2] = {0.f, 0.f};
#pragma unroll
  for (int pr = 0; pr < 2; ++pr)
#pragma unroll
    for (int cb = 0; cb < 8; ++cb)
#pragma unroll
      for (int r = 0; r < 4; ++r) {
        float v = acc[pr][cb][r];
        on[(size_t)(co0 + pr * 16 + lg * 4 + r) * HW + p0 + cb * 16 + lr] = f2bf(v);
        s[pr] += v; ss[pr] += v * v;
      }
#pragma unroll
  for (int pr = 0; pr < 2; ++pr) {
    float a = s[pr], b = ss[pr];
    for (int m = 1; m < 64; m <<= 1) { a += __shfl_xor(a, m); b += __shfl_xor(b, m); }
    if (lane == 0) {
      float* pp = part + ((((size_t)n * 4 + zc) * 128 + blockIdx.x) * 8 + wv * 2 + pr) * 2;
      pp[0] = a; pp[1] = b;
    }
  }
}

// gnf3 wide: 1024 threads
__global__ __launch_bounds__(1024) void gnf3_kernel(
    const float* __restrict__ part, float* __restrict__ stats) {
  __shared__ float sh[1024], sh2[1024];
  int t = threadIdx.x;
  int e = t >> 3, xbs = t & 7;
  int n = e >> 5, g = e & 31;
  int zc = g >> 3, sub = g & 7;
  float s = 0.f, ss = 0.f;
  for (int xb = xbs * 16; xb < xbs * 16 + 16; ++xb) {
    const float* pp = part + ((((size_t)n * 4 + zc) * 128 + xb) * 8 + sub) * 2;
    s += pp[0]; ss += pp[1];
  }
  sh[t] = s; sh2[t] = ss;
  __syncthreads();
  if (t < 128) {
    float a = 0.f, b2 = 0.f;
#pragma unroll
    for (int i = 0; i < 8; ++i) { a += sh[t * 8 + i]; b2 += sh2[t * 8 + i]; }
    float inv = 1.f / (16.f * HW);
    float mean = a * inv, var = b2 * inv - mean * mean;
    stats[2 * t] = mean; stats[2 * t + 1] = rsqrtf(var + 1e-5f);
  }
}

// stage-3 GN apply (R11): read y3b bf16 channel-major, write fp32 d_out (+ReLU)
__global__ __launch_bounds__(256) void gn3_apply_kernel(
    const unsigned short* __restrict__ y3b, const float* __restrict__ stats,
    const float* __restrict__ gamma, const float* __restrict__ beta,
    float* __restrict__ out) {
  size_t e8 = ((size_t)blockIdx.x * 256 + threadIdx.x) * 8;
  int n = (int)(e8 >> 23);
  int c = (int)((e8 >> 14) & 511);
  int sg = n * 32 + (c >> 4);
  float mean = stats[2 * sg], rstd = stats[2 * sg + 1];
  float scale = rstd * gamma[c];
  float shift = beta[c] - mean * scale;
  u16x8 u = *(const u16x8*)(y3b + e8);
  float4 o0, o1;
  o0.x = fmaxf(fmaf(bf2f(u[0]), scale, shift), 0.f);
  o0.y = fmaxf(fmaf(bf2f(u[1]), scale, shift), 0.f);
  o0.z = fmaxf(fmaf(bf2f(u[2]), scale, shift), 0.f);
  o0.w = fmaxf(fmaf(bf2f(u[3]), scale, shift), 0.f);
  o1.x = fmaxf(fmaf(bf2f(u[4]), scale, shift), 0.f);
  o1.y = fmaxf(fmaf(bf2f(u[5]), scale, shift), 0.f);
  o1.z = fmaxf(fmaf(bf2f(u[6]), scale, shift), 0.f);
  o1.w = fmaxf(fmaf(bf2f(u[7]), scale, shift), 0.f);
  *(float4*)(out + e8) = o0;
  *(float4*)(out + e8 + 4) = o1;
}

// ---------------------------------------------------------------------------
// dynfused9<D>: 32-px quarter-row tile, 512 threads, dilation as template
// param (compile-time tap addressing/masks), one launch per branch.
// LDS = 3*56*272 B + 32*17*4 B = 47872 B -> 3 blocks/CU.
// outb points at cat + 128*(br+1) column offset.
// ---------------------------------------------------------------------------
#define DP 136     // u16 per px slot (272 B)
#define DSLOTS 56  // 32 px + 2*12 halo

template<int D>
__global__ __launch_bounds__(512, 6) void dynfused9_kernel(
    const unsigned short* __restrict__ cat, const unsigned short* __restrict__ wb,
    unsigned short* __restrict__ outb) {
  extern __shared__ char smem[];
  unsigned short* rowbuf = (unsigned short*)smem;             // 3*DSLOTS*DP u16
  float* fl = (float*)(smem + 3 * DSLOTS * DP * 2);           // [32][17] f32
  int t = threadIdx.x;
  int bid = blockIdx.x;
  int rh = ((bid & 7) << 6) + (bid >> 3);   // XCD: 64 consecutive quarter-rows
  int row = rh >> 2, qw = rh & 3;
  int n = blockIdx.y;
  const unsigned short* xb = cat + (size_t)n * HW * 640;

  int rg[3] = { max(row - D, 0), row, min(row + D, 127) };
  bool rv[3] = { row - D >= 0, true, row + D < 128 };
  int cbase = qw * 32 - 12;                 // global col of staged slot 0

  // ---- batched staging: 3 rows x 56 slots x 16 chunks = 2688 u16x8 chunks
  {
    u16x8 vreg[6];
#pragma unroll
    for (int k = 0; k < 6; ++k) {
      int ci = t + (k << 9);
      if (k == 5 && ci >= 2688) continue;
      int s = (ci >= 1792) ? 2 : (ci >= 896 ? 1 : 0);
      int rem = ci - s * 896;
      int slot = rem >> 4, c = rem & 15;
      int gcol = min(max(cbase + slot, 0), 127);
      vreg[k] = *(const u16x8*)(xb + ((size_t)(rg[s] * 128 + gcol)) * 640 + c * 8);
    }
#pragma unroll
    for (int k = 0; k < 6; ++k) {
      int ci = t + (k << 9);
      if (k == 5 && ci >= 2688) continue;
      int s = (ci >= 1792) ? 2 : (ci >= 896 ? 1 : 0);
      int rem = ci - s * 896;
      int slot = rem >> 4, c = rem & 15;
      *(u16x8*)(rowbuf + ((size_t)s * DSLOTS + slot) * DP + c * 8) = vreg[k];
    }
  }
  __syncthreads();

  // Phase 1: filter conv via MFMA on waves 0-1; wave wv -> px [wv*16, +16)
  if (t < 128) {
    int wv = t >> 6, lane = t & 63;
    int lr = lane & 15, lg = lane >> 4;
    const bf16x8 zb = {(__bf16)0.f, (__bf16)0.f, (__bf16)0.f, (__bf16)0.f,
                       (__bf16)0.f, (__bf16)0.f, (__bf16)0.f, (__bf16)0.f};
    f32x4 acc = (f32x4){0.f, 0.f, 0.f, 0.f};
    int pxl = wv * 16 + lr;                 // local out px 0..31
    int gw = qw * 32 + pxl;                 // global col
#pragma unroll
    for (int tap = 0; tap < 9; ++tap) {
      const int s = tap / 3;
      const int dw = (tap % 3 - 1) * D;
      int slot = 12 + pxl + dw;             // in [0,56)
      bool val = rv[s] && ((unsigned)(gw + dw) < 128u);
      const unsigned short* ap = rowbuf + ((size_t)s * DSLOTS + slot) * DP + lg * 8;
      const unsigned short* wt = wb + (size_t)(tap * 16 + lr) * 128 + lg * 8;
#pragma unroll
      for (int ks = 0; ks < 4; ++ks) {
        bf16x8 a = *(const bf16x8*)(ap + ks * 32);
        if (!val) a = zb;
        bf16x8 b = *(const bf16x8*)(wt + ks * 32);
        acc = __builtin_amdgcn_mfma_f32_16x16x32_bf16(a, b, acc, 0, 0, 0);
      }
    }
#pragma unroll
    for (int r = 0; r < 4; ++r) {
      float v = acc[r];
      float m = (lr < 9) ? v : -3.0e38f;
#pragma unroll
      for (int msk = 1; msk < 16; msk <<= 1) m = fmaxf(m, __shfl_xor(m, msk));
      float e = (lr < 9) ? expf(v - m) : 0.f;
      float su = e;
#pragma unroll
      for (int msk = 1; msk < 16; msk <<= 1) su += __shfl_xor(su, msk);
      fl[(wv * 16 + lg * 4 + r) * 17 + lr] = e / su;
    }
  }
  __syncthreads();

  // Phase 2: thread (pxl = t>>4, c16 = t&15) accumulates 8 ch of its pixel
  {
    int pxl = t >> 4, c16 = t & 15;
    int gw = qw * 32 + pxl;
    float oacc[8];
#pragma unroll
    for (int i = 0; i < 8; ++i) oacc[i] = 0.f;
#pragma unroll
    for (int tap = 0; tap < 9; ++tap) {
      const int s = tap / 3;
      const int dw = (tap % 3 - 1) * D;
      int slot = 12 + pxl + dw;
      bool val = rv[s] && ((unsigned)(gw + dw) < 128u);
      float f = val ? fl[pxl * 17 + tap] : 0.f;
      u16x8 u = *(const u16x8*)(rowbuf + ((size_t)s * DSLOTS + slot) * DP + c16 * 8);
#pragma unroll
      for (int i = 0; i < 8; ++i)
        oacc[i] = fmaf(f, bf2f(u[i]), oacc[i]);
    }
    unsigned short* orow = outb + ((size_t)n * HW + row * 128 + gw) * 640 + c16 * 8;
    u16x8 o;
#pragma unroll
    for (int i = 0; i < 8; ++i) o[i] = f2bf(oacc[i]);
    *(u16x8*)orow = o;
  }
}

// ---------------------------------------------------------------------------
extern "C" void kernel_launch(void* const* d_in, const int* in_sizes, int n_in,
                              void* d_out, int out_size, void* d_ws, size_t ws_size,
                              hipStream_t stream) {
  const float* x   = (const float*)d_in[0];
  const float* w1  = (const float*)d_in[1];
  const float* g1  = (const float*)d_in[2];
  const float* b1  = (const float*)d_in[3];
  const float* wca = (const float*)d_in[4];
  const float* wcb = (const float*)d_in[5];
  const float* wcc = (const float*)d_in[6];
  const float* wcd = (const float*)d_in[7];
  const float* w2  = (const float*)d_in[8];
  const float* g2  = (const float*)d_in[9];
  const float* b2  = (const float*)d_in[10];
  const float* w3  = (const float*)d_in[11];
  const float* g3  = (const float*)d_in[12];
  const float* b3  = (const float*)d_in[13];
  float* out = (float*)d_out;

  float* ws = (float*)d_ws;
  unsigned short* cat = (unsigned short*)(ws + 25165824);  // (n,HW,640) bf16
  unsigned short* y2b = (unsigned short*)(ws + 8388608);   // bf16 (n,HW,128)
  unsigned short* y3b = (unsigned short*)(ws + 25165824);  // overlay cat
  float* aux = ws + 46137344;
  unsigned short* w1b = (unsigned short*)(aux);
  unsigned short* w2b = (unsigned short*)(aux + 32768);
  unsigned short* w3b = (unsigned short*)(aux + 73728);
  unsigned short* wr  = (unsigned short*)(aux + 106496);
  float* part  = aux + 143360;                             // 65536 f
  float* part3 = aux + 208896;                             // 32768 f
  float* st1   = aux + 241664;
  float* st2   = aux + 241920;
  float* st3   = aux + 242176;

  dim3 blk(256);
  const int dynLds = 3 * DSLOTS * DP * 2 + 32 * 17 * 4;  // 47872 B
  (void)hipFuncSetAttribute((const void*)dynfused9_kernel<1>,
                            hipFuncAttributeMaxDynamicSharedMemorySize, dynLds);
  (void)hipFuncSetAttribute((const void*)dynfused9_kernel<4>,
                            hipFuncAttributeMaxDynamicSharedMemorySize, dynLds);
  (void)hipFuncSetAttribute((const void*)dynfused9_kernel<8>,
                            hipFuncAttributeMaxDynamicSharedMemorySize, dynLds);
  (void)hipFuncSetAttribute((const void*)dynfused9_kernel<12>,
                            hipFuncAttributeMaxDynamicSharedMemorySize, dynLds);

  prep_kernel<<<dim3(1120), blk, 0, stream>>>(w1, w2, w3, wca, wcb, wcc, wcd,
                                              w1b, w2b, w3b, wr);

  // stage 1: fused transpose+conv + GN1 partials -> cat 0..127 raw; stats; norm
  conv1f_kernel<<<dim3(256, 4), blk, 0, stream>>>(x, w1b, cat, part);
  gnf256_kernel<<<dim3(1), dim3(1024), 0, stream>>>(part, st1);
  gna_ip_kernel<<<dim3(8192), blk, 0, stream>>>(cat, st1, g1, b1, 640);

  // four fused dynamic branches (one launch per branch, compile-time dilation)
  dynfused9_kernel<1> <<<dim3(512, 4), dim3(512), dynLds, stream>>>(
      cat, wr + 0 * 18432, cat + 128);
  dynfused9_kernel<4> <<<dim3(512, 4), dim3(512), dynLds, stream>>>(
      cat, wr + 1 * 18432, cat + 256);
  dynfused9_kernel<8> <<<dim3(512, 4), dim3(512), dynLds, stream>>>(
      cat, wr + 2 * 18432, cat + 384);
  dynfused9_kernel<12><<<dim3(512, 4), dim3(512), dynLds, stream>>>(
      cat, wr + 3 * 18432, cat + 512);

  // stage 2: conv 640->128 + GN2 partials -> y2b raw; stats; in-place norm
  conv_pm_kernel<640><<<dim3(256, 4), blk, 0, stream>>>(cat, w2b, y2b, part, 128);
  gnf256_kernel<<<dim3(1), dim3(1024), 0, stream>>>(part, st2);
  gna_ip_kernel<<<dim3(8192), blk, 0, stream>>>(y2b, st2, g2, b2, 128);

  // stage 3: conv 128->512 -> y3b bf16 + GN3 partials; stats; apply -> out
  conv3_kernel<<<dim3(128, 4, 4), blk, 0, stream>>>(y2b, w3b, y3b, part3);
  gnf3_kernel<<<dim3(1), dim3(1024), 0, stream>>>(part3, st3);
  gn3_apply_kernel<<<dim3(16384), blk, 0, stream>>>(y3b, st3, g3, b3, out);
}

// Round 17
// 371.465 us; speedup vs baseline: 1.0916x; 1.0916x over previous
//
#include <hip/hip_runtime.h>
#include <math.h>

#define HW 16384

typedef float f32x4 __attribute__((ext_vector_type(4)));
typedef __bf16 bf16x8 __attribute__((ext_vector_type(8)));
typedef unsigned short u16x4 __attribute__((ext_vector_type(4)));
typedef unsigned short u16x8 __attribute__((ext_vector_type(8)));

__device__ __forceinline__ unsigned short f2bf(float f) {
  unsigned u = __float_as_uint(f);
  u += 0x7fffu + ((u >> 16) & 1u);
  return (unsigned short)(u >> 16);
}
__device__ __forceinline__ float bf2f(unsigned short s) {
  return __uint_as_float(((unsigned)s) << 16);
}

// ---------------------------------------------------------------------------
// prep: w1,w2,w3 fp32 -> bf16; wr[br][tap][kt(16,pad)][c(128)] from (9,128,3,3)
// ---------------------------------------------------------------------------
__global__ void prep_kernel(const float* __restrict__ w1, const float* __restrict__ w2,
                            const float* __restrict__ w3,
                            const float* __restrict__ wa, const float* __restrict__ wb,
                            const float* __restrict__ wc, const float* __restrict__ wd,
                            unsigned short* __restrict__ w1b, unsigned short* __restrict__ w2b,
                            unsigned short* __restrict__ w3b, unsigned short* __restrict__ wr) {
  int idx = blockIdx.x * 256 + threadIdx.x;
  if (idx < 65536) { w1b[idx] = f2bf(w1[idx]); }
  else if (idx < 147456) { int j = idx - 65536; w2b[j] = f2bf(w2[j]); }
  else if (idx < 212992) { int j = idx - 147456; w3b[j] = f2bf(w3[j]); }
  else if (idx < 286720) {
    int j = idx - 212992;
    int br = j / 18432, rem = j % 18432;
    int tap = rem / 2048, rem2 = rem % 2048;
    int kt = rem2 / 128, c = rem2 % 128;
    const float* w = (br == 0) ? wa : (br == 1) ? wb : (br == 2) ? wc : wd;
    float v = (kt < 9) ? w[(kt * 128 + c) * 9 + tap] : 0.f;
    wr[j] = f2bf(v);
  }
}

// ---------------------------------------------------------------------------
// GN partial-stats epilogue helper.
// part layout: [((n*32+g)*256 + blkx)*2 + {0,1}]
// ---------------------------------------------------------------------------
__device__ __forceinline__ void gn_partial_epilogue(
    f32x4 (&acc)[8], int wv, int lane, int t, int n, int blkx,
    float* __restrict__ part, float (*ps)[32], float (*pss)[32]) {
  float gs[8], gss[8];
#pragma unroll
  for (int cb = 0; cb < 8; ++cb) {
    float s = 0.f, ss = 0.f;
#pragma unroll
    for (int r = 0; r < 4; ++r) { float v = acc[cb][r]; s += v; ss += v * v; }
#pragma unroll
    for (int m = 0; m < 4; ++m) {
      const int msk[4] = {1, 2, 16, 32};
      s += __shfl_xor(s, msk[m]); ss += __shfl_xor(ss, msk[m]);
    }
    gs[cb] = s; gss[cb] = ss;
  }
  if (lane < 16 && (lane & 3) == 0) {
    int q = lane >> 2;
#pragma unroll
    for (int cb = 0; cb < 8; ++cb) { ps[wv][cb * 4 + q] = gs[cb]; pss[wv][cb * 4 + q] = gss[cb]; }
  }
  __syncthreads();
  if (t < 32) {
    float a = ps[0][t] + ps[1][t] + ps[2][t] + ps[3][t];
    float b = pss[0][t] + pss[1][t] + pss[2][t] + pss[3][t];
    float* pp = part + ((size_t)(n * 32 + t) * 256 + blkx) * 2;
    pp[0] = a; pp[1] = b;
  }
}

// ---------------------------------------------------------------------------
// conv1f (R11): fused transpose + 1x1 conv 512->128, dbuf staging,
// LDS [ch][px] (+1 pad). Raw bf16 out (cat cols 0..127) + fused GN1 partials.
// ---------------------------------------------------------------------------
__global__ __launch_bounds__(256) void conv1f_kernel(
    const float* __restrict__ x, const unsigned short* __restrict__ w1b,
    unsigned short* __restrict__ outb, float* __restrict__ part) {
  __shared__ float xs[2][64][65];
  __shared__ float ps[4][32], pss[4][32];
  int t = threadIdx.x;
  int wv = t >> 6, lane = t & 63, lr = lane & 15, lg = lane >> 4;
  int n = blockIdx.y;
  int p0 = blockIdx.x * 64;
  const float* xn = x + (size_t)n * 512 * HW + p0;
  f32x4 acc[8];
#pragma unroll
  for (int cb = 0; cb < 8; ++cb) acc[cb] = (f32x4){0.f, 0.f, 0.f, 0.f};

  int ci_l = t >> 4, px4 = (t & 15) * 4;
  float4 r[4];

#pragma unroll
  for (int pass = 0; pass < 4; ++pass)
    r[pass] = *(const float4*)(xn + (size_t)(pass * 16 + ci_l) * HW + px4);
#pragma unroll
  for (int pass = 0; pass < 4; ++pass) {
    int cl = pass * 16 + ci_l;
    xs[0][cl][px4 + 0] = r[pass].x; xs[0][cl][px4 + 1] = r[pass].y;
    xs[0][cl][px4 + 2] = r[pass].z; xs[0][cl][px4 + 3] = r[pass].w;
  }

  for (int kt = 0; kt < 8; ++kt) {
    int cur = kt & 1;
    if (kt < 7) {
#pragma unroll
      for (int pass = 0; pass < 4; ++pass)
        r[pass] = *(const float4*)(xn + (size_t)((kt + 1) * 64 + pass * 16 + ci_l) * HW + px4);
    }
    __syncthreads();
#pragma unroll
    for (int ks = 0; ks < 2; ++ks) {
      bf16x8 a;
#pragma unroll
      for (int j = 0; j < 8; ++j) {
        unsigned short us = f2bf(xs[cur][ks * 32 + lg * 8 + j][wv * 16 + lr]);
        a[j] = *(__bf16*)&us;
      }
#pragma unroll
      for (int cb = 0; cb < 8; ++cb) {
        bf16x8 b = *(const bf16x8*)(w1b + (size_t)(cb * 16 + lr) * 512
                                    + kt * 64 + ks * 32 + lg * 8);
        acc[cb] = __builtin_amdgcn_mfma_f32_16x16x32_bf16(a, b, acc[cb], 0, 0, 0);
      }
    }
    if (kt < 7) {
#pragma unroll
      for (int pass = 0; pass < 4; ++pass) {
        int cl = pass * 16 + ci_l;
        xs[cur ^ 1][cl][px4 + 0] = r[pass].x; xs[cur ^ 1][cl][px4 + 1] = r[pass].y;
        xs[cur ^ 1][cl][px4 + 2] = r[pass].z; xs[cur ^ 1][cl][px4 + 3] = r[pass].w;
      }
    }
  }
  unsigned short* on = outb + (size_t)n * HW * 640;
#pragma unroll
  for (int cb = 0; cb < 8; ++cb)
#pragma unroll
    for (int r2 = 0; r2 < 4; ++r2)
      on[(size_t)(p0 + wv * 16 + lg * 4 + r2) * 640 + cb * 16 + lr] = f2bf(acc[cb][r2]);
  __syncthreads();
  gn_partial_epilogue(acc, wv, lane, t, n, blockIdx.x, part, ps, pss);
}

// ---------------------------------------------------------------------------
// conv2 MFMA, 64-px blocks, REGISTER-PIPELINED K loop (prefetch ks+1 A+B),
// raw bf16 out + fused GN2 partials.
// ---------------------------------------------------------------------------
template<int K>
__global__ __launch_bounds__(256) void conv_pm_kernel(
    const unsigned short* __restrict__ act, const unsigned short* __restrict__ w,
    unsigned short* __restrict__ outb, float* __restrict__ part, int ldd) {
  __shared__ float ps[4][32], pss[4][32];
  int t = threadIdx.x;
  int wv = t >> 6, lane = t & 63;
  int lr = lane & 15, lg = lane >> 4;
  int n = blockIdx.y;
  int p0 = blockIdx.x * 64 + wv * 16;
  const unsigned short* an = act + (size_t)n * HW * K;
  f32x4 acc[8];
#pragma unroll
  for (int cb = 0; cb < 8; ++cb) acc[cb] = (f32x4){0.f, 0.f, 0.f, 0.f};
  const unsigned short* ap = an + (size_t)(p0 + lr) * K + lg * 8;
  const unsigned short* bp = w + (size_t)lr * K + lg * 8;
  constexpr int NK = K / 32;

  bf16x8 a_c, b_c[8], a_n, b_n[8];
  a_c = *(const bf16x8*)(ap);
#pragma unroll
  for (int cb = 0; cb < 8; ++cb) b_c[cb] = *(const bf16x8*)(bp + (size_t)cb * 16 * K);

#pragma unroll
  for (int ks = 0; ks < NK; ++ks) {
    if (ks + 1 < NK) {
      a_n = *(const bf16x8*)(ap + (ks + 1) * 32);
#pragma unroll
      for (int cb = 0; cb < 8; ++cb)
        b_n[cb] = *(const bf16x8*)(bp + (size_t)cb * 16 * K + (ks + 1) * 32);
    }
#pragma unroll
    for (int cb = 0; cb < 8; ++cb)
      acc[cb] = __builtin_amdgcn_mfma_f32_16x16x32_bf16(a_c, b_c[cb], acc[cb], 0, 0, 0);
    if (ks + 1 < NK) {
      a_c = a_n;
#pragma unroll
      for (int cb = 0; cb < 8; ++cb) b_c[cb] = b_n[cb];
    }
  }
  unsigned short* on = outb + (size_t)n * HW * ldd;
#pragma unroll
  for (int cb = 0; cb < 8; ++cb)
#pragma unroll
    for (int r = 0; r < 4; ++r)
      on[(size_t)(p0 + lg * 4 + r) * ldd + cb * 16 + lr] = f2bf(acc[cb][r]);
  gn_partial_epilogue(acc, wv, lane, t, n, blockIdx.x, part, ps, pss);
}

// gnf256 wide: 1024 threads, 8-way split per (n,g); count = 4ch*HW
__global__ __launch_bounds__(1024) void gnf256_kernel(
    const float* __restrict__ part, float* __restrict__ stats) {
  __shared__ float sh[1024], sh2[1024];
  int t = threadIdx.x;
  int tg = t >> 3, sub = t & 7;
  float s = 0.f, ss = 0.f;
  for (int b = sub * 32; b < sub * 32 + 32; ++b) {
    const float* pp = part + ((size_t)tg * 256 + b) * 2;
    s += pp[0]; ss += pp[1];
  }
  sh[t] = s; sh2[t] = ss;
  __syncthreads();
  if (t < 128) {
    float a = 0.f, b2 = 0.f;
#pragma unroll
    for (int i = 0; i < 8; ++i) { a += sh[t * 8 + i]; b2 += sh2[t * 8 + i]; }
    float inv = 1.f / (4.f * HW);
    float mean = a * inv, var = b2 * inv - mean * mean;
    stats[2 * t] = mean; stats[2 * t + 1] = rsqrtf(var + 1e-5f);
  }
}

// GN apply IN PLACE on bf16 buffer (+ReLU), row stride ldd
__global__ __launch_bounds__(256) void gna_ip_kernel(
    unsigned short* __restrict__ dst, const float* __restrict__ stats,
    const float* __restrict__ gamma, const float* __restrict__ beta, int ldd) {
  int idx = blockIdx.x * 256 + threadIdx.x;
  int g = idx & 31;
  int p = (idx >> 5) & (HW - 1);
  int n = idx >> 19;
  unsigned short* ptr = dst + ((size_t)n * HW + p) * ldd + 4 * g;
  u16x4 v = *(u16x4*)ptr;
  int sg = n * 32 + g;
  float mean = stats[2 * sg], rstd = stats[2 * sg + 1];
  float sc0 = rstd * gamma[4 * g + 0], sc1 = rstd * gamma[4 * g + 1];
  float sc2 = rstd * gamma[4 * g + 2], sc3 = rstd * gamma[4 * g + 3];
  float sh0 = beta[4 * g + 0] - mean * sc0, sh1 = beta[4 * g + 1] - mean * sc1;
  float sh2 = beta[4 * g + 2] - mean * sc2, sh3 = beta[4 * g + 3] - mean * sc3;
  u16x4 o;
  o[0] = f2bf(fmaxf(fmaf(bf2f(v[0]), sc0, sh0), 0.f));
  o[1] = f2bf(fmaxf(fmaf(bf2f(v[1]), sc1, sh1), 0.f));
  o[2] = f2bf(fmaxf(fmaf(bf2f(v[2]), sc2, sh2), 0.f));
  o[3] = f2bf(fmaxf(fmaf(bf2f(v[3]), sc3, sh3), 0.f));
  *(u16x4*)ptr = o;
}

// ---------------------------------------------------------------------------
// conv3 MFMA (R11 one-pass) -> y3b bf16 channel-major + fused GN3 partials
// ---------------------------------------------------------------------------
__global__ __launch_bounds__(256) void conv3_kernel(
    const unsigned short* __restrict__ y, const unsigned short* __restrict__ w3,
    unsigned short* __restrict__ outb, float* __restrict__ part) {
  int wv = threadIdx.x >> 6, lane = threadIdx.x & 63;
  int lr = lane & 15, lg = lane >> 4;
  int n = blockIdx.y, zc = blockIdx.z;
  int co0 = zc * 128 + wv * 32;
  int p0 = blockIdx.x * 128;
  const unsigned short* yn = y + (size_t)n * HW * 128;
  f32x4 acc[2][8];
#pragma unroll
  for (int pr = 0; pr < 2; ++pr)
#pragma unroll
    for (int cb = 0; cb < 8; ++cb) acc[pr][cb] = (f32x4){0.f, 0.f, 0.f, 0.f};
#pragma unroll
  for (int ks = 0; ks < 4; ++ks) {
    bf16x8 a0 = *(const bf16x8*)(w3 + (size_t)(co0 + lr) * 128 + ks * 32 + lg * 8);
    bf16x8 a1 = *(const bf16x8*)(w3 + (size_t)(co0 + 16 + lr) * 128 + ks * 32 + lg * 8);
#pragma unroll
    for (int cb = 0; cb < 8; ++cb) {
      bf16x8 b = *(const bf16x8*)(yn + (size_t)(p0 + cb * 16 + lr) * 128 + ks * 32 + lg * 8);
      acc[0][cb] = __builtin_amdgcn_mfma_f32_16x16x32_bf16(a0, b, acc[0][cb], 0, 0, 0);
      acc[1][cb] = __builtin_amdgcn_mfma_f32_16x16x32_bf16(a1, b, acc[1][cb], 0, 0, 0);
    }
  }
  unsigned short* on = outb + (size_t)n * 512 * HW;
  float s[2] = {0.f, 0.f}, ss[2] = {0.f, 0.f};
#pragma unroll
  for (int pr = 0; pr < 2; ++pr)
#pragma unroll
    for (int cb = 0; cb < 8; ++cb)
#pragma unroll
      for (int r = 0; r < 4; ++r) {
        float v = acc[pr][cb][r];
        on[(size_t)(co0 + pr * 16 + lg * 4 + r) * HW + p0 + cb * 16 + lr] = f2bf(v);
        s[pr] += v; ss[pr] += v * v;
      }
#pragma unroll
  for (int pr = 0; pr < 2; ++pr) {
    float a = s[pr], b = ss[pr];
    for (int m = 1; m < 64; m <<= 1) { a += __shfl_xor(a, m); b += __shfl_xor(b, m); }
    if (lane == 0) {
      float* pp = part + ((((size_t)n * 4 + zc) * 128 + blockIdx.x) * 8 + wv * 2 + pr) * 2;
      pp[0] = a; pp[1] = b;
    }
  }
}

// gnf3 wide: 1024 threads
__global__ __launch_bounds__(1024) void gnf3_kernel(
    const float* __restrict__ part, float* __restrict__ stats) {
  __shared__ float sh[1024], sh2[1024];
  int t = threadIdx.x;
  int e = t >> 3, xbs = t & 7;
  int n = e >> 5, g = e & 31;
  int zc = g >> 3, sub = g & 7;
  float s = 0.f, ss = 0.f;
  for (int xb = xbs * 16; xb < xbs * 16 + 16; ++xb) {
    const float* pp = part + ((((size_t)n * 4 + zc) * 128 + xb) * 8 + sub) * 2;
    s += pp[0]; ss += pp[1];
  }
  sh[t] = s; sh2[t] = ss;
  __syncthreads();
  if (t < 128) {
    float a = 0.f, b2 = 0.f;
#pragma unroll
    for (int i = 0; i < 8; ++i) { a += sh[t * 8 + i]; b2 += sh2[t * 8 + i]; }
    float inv = 1.f / (16.f * HW);
    float mean = a * inv, var = b2 * inv - mean * mean;
    stats[2 * t] = mean; stats[2 * t + 1] = rsqrtf(var + 1e-5f);
  }
}

// stage-3 GN apply (R11): read y3b bf16 channel-major, write fp32 d_out (+ReLU)
__global__ __launch_bounds__(256) void gn3_apply_kernel(
    const unsigned short* __restrict__ y3b, const float* __restrict__ stats,
    const float* __restrict__ gamma, const float* __restrict__ beta,
    float* __restrict__ out) {
  size_t e8 = ((size_t)blockIdx.x * 256 + threadIdx.x) * 8;
  int n = (int)(e8 >> 23);
  int c = (int)((e8 >> 14) & 511);
  int sg = n * 32 + (c >> 4);
  float mean = stats[2 * sg], rstd = stats[2 * sg + 1];
  float scale = rstd * gamma[c];
  float shift = beta[c] - mean * scale;
  u16x8 u = *(const u16x8*)(y3b + e8);
  float4 o0, o1;
  o0.x = fmaxf(fmaf(bf2f(u[0]), scale, shift), 0.f);
  o0.y = fmaxf(fmaf(bf2f(u[1]), scale, shift), 0.f);
  o0.z = fmaxf(fmaf(bf2f(u[2]), scale, shift), 0.f);
  o0.w = fmaxf(fmaf(bf2f(u[3]), scale, shift), 0.f);
  o1.x = fmaxf(fmaf(bf2f(u[4]), scale, shift), 0.f);
  o1.y = fmaxf(fmaf(bf2f(u[5]), scale, shift), 0.f);
  o1.z = fmaxf(fmaf(bf2f(u[6]), scale, shift), 0.f);
  o1.w = fmaxf(fmaf(bf2f(u[7]), scale, shift), 0.f);
  *(float4*)(out + e8) = o0;
  *(float4*)(out + e8 + 4) = o1;
}

// ---------------------------------------------------------------------------
// dynfused8 (R15): 32-px quarter-row tile, 512 threads, all 4 branches in
// one grid (blockIdx.y = n*4+br). LDS 47872 B -> 3 blocks/CU.
// ---------------------------------------------------------------------------
#define DP 136     // u16 per px slot (272 B)
#define DSLOTS 56  // 32 px + 2*12 halo

__global__ __launch_bounds__(512, 6) void dynfused8_kernel(
    const unsigned short* __restrict__ cat, const unsigned short* __restrict__ wr,
    unsigned short* __restrict__ catw) {
  extern __shared__ char smem[];
  unsigned short* rowbuf = (unsigned short*)smem;             // 3*DSLOTS*DP u16
  float* fl = (float*)(smem + 3 * DSLOTS * DP * 2);           // [32][17] f32
  int t = threadIdx.x;
  int bid = blockIdx.x;
  int rh = ((bid & 7) << 6) + (bid >> 3);   // XCD: 64 consecutive quarter-rows
  int row = rh >> 2, qw = rh & 3;
  int n = blockIdx.y >> 2, br = blockIdx.y & 3;
  int d = (br == 0) ? 1 : 4 * br;
  const unsigned short* xb = cat + (size_t)n * HW * 640;

  int rg[3] = { max(row - d, 0), row, min(row + d, 127) };
  bool rv[3] = { row - d >= 0, true, row + d < 128 };
  int cbase = qw * 32 - 12;                 // global col of staged slot 0

  // ---- batched staging: 3 rows x 56 slots x 16 chunks = 2688 u16x8 chunks
  {
    u16x8 vreg[6];
#pragma unroll
    for (int k = 0; k < 6; ++k) {
      int ci = t + (k << 9);
      if (k == 5 && ci >= 2688) continue;
      int s = (ci >= 1792) ? 2 : (ci >= 896 ? 1 : 0);
      int rem = ci - s * 896;
      int slot = rem >> 4, c = rem & 15;
      int gcol = min(max(cbase + slot, 0), 127);
      vreg[k] = *(const u16x8*)(xb + ((size_t)(rg[s] * 128 + gcol)) * 640 + c * 8);
    }
#pragma unroll
    for (int k = 0; k < 6; ++k) {
      int ci = t + (k << 9);
      if (k == 5 && ci >= 2688) continue;
      int s = (ci >= 1792) ? 2 : (ci >= 896 ? 1 : 0);
      int rem = ci - s * 896;
      int slot = rem >> 4, c = rem & 15;
      *(u16x8*)(rowbuf + ((size_t)s * DSLOTS + slot) * DP + c * 8) = vreg[k];
    }
  }
  __syncthreads();

  // Phase 1: filter conv via MFMA on waves 0-1; wave wv -> px [wv*16, +16)
  if (t < 128) {
    int wv = t >> 6, lane = t & 63;
    int lr = lane & 15, lg = lane >> 4;
    const unsigned short* wb = wr + (size_t)br * 9 * 16 * 128;
    const bf16x8 zb = {(__bf16)0.f, (__bf16)0.f, (__bf16)0.f, (__bf16)0.f,
                       (__bf16)0.f, (__bf16)0.f, (__bf16)0.f, (__bf16)0.f};
    f32x4 acc = (f32x4){0.f, 0.f, 0.f, 0.f};
    int pxl = wv * 16 + lr;                 // local out px 0..31
    int gw = qw * 32 + pxl;                 // global col
#pragma unroll
    for (int tap = 0; tap < 9; ++tap) {
      int s = tap / 3;
      int dw = (tap % 3 - 1) * d;
      int slot = 12 + pxl + dw;             // in [0,56)
      bool val = rv[s] && ((unsigned)(gw + dw) < 128u);
      const unsigned short* ap = rowbuf + ((size_t)s * DSLOTS + slot) * DP + lg * 8;
      const unsigned short* wt = wb + (size_t)(tap * 16 + lr) * 128 + lg * 8;
#pragma unroll
      for (int ks = 0; ks < 4; ++ks) {
        bf16x8 a = *(const bf16x8*)(ap + ks * 32);
        if (!val) a = zb;
        bf16x8 b = *(const bf16x8*)(wt + ks * 32);
        acc = __builtin_amdgcn_mfma_f32_16x16x32_bf16(a, b, acc, 0, 0, 0);
      }
    }
#pragma unroll
    for (int r = 0; r < 4; ++r) {
      float v = acc[r];
      float m = (lr < 9) ? v : -3.0e38f;
#pragma unroll
      for (int msk = 1; msk < 16; msk <<= 1) m = fmaxf(m, __shfl_xor(m, msk));
      float e = (lr < 9) ? expf(v - m) : 0.f;
      float su = e;
#pragma unroll
      for (int msk = 1; msk < 16; msk <<= 1) su += __shfl_xor(su, msk);
      fl[(wv * 16 + lg * 4 + r) * 17 + lr] = e / su;
    }
  }
  __syncthreads();

  // Phase 2: thread (pxl = t>>4, c16 = t&15) accumulates 8 ch of its pixel
  {
    int pxl = t >> 4, c16 = t & 15;
    int gw = qw * 32 + pxl;
    float oacc[8];
#pragma unroll
    for (int i = 0; i < 8; ++i) oacc[i] = 0.f;
#pragma unroll
    for (int tap = 0; tap < 9; ++tap) {
      int s = tap / 3;
      int dw = (tap % 3 - 1) * d;
      int slot = 12 + pxl + dw;
      bool val = rv[s] && ((unsigned)(gw + dw) < 128u);
      float f = val ? fl[pxl * 17 + tap] : 0.f;
      u16x8 u = *(const u16x8*)(rowbuf + ((size_t)s * DSLOTS + slot) * DP + c16 * 8);
#pragma unroll
      for (int i = 0; i < 8; ++i)
        oacc[i] = fmaf(f, bf2f(u[i]), oacc[i]);
    }
    unsigned short* orow = catw + ((size_t)n * HW + row * 128 + gw) * 640
                           + 128 * (br + 1) + c16 * 8;
    u16x8 o;
#pragma unroll
    for (int i = 0; i < 8; ++i) o[i] = f2bf(oacc[i]);
    *(u16x8*)orow = o;
  }
}

// ---------------------------------------------------------------------------
extern "C" void kernel_launch(void* const* d_in, const int* in_sizes, int n_in,
                              void* d_out, int out_size, void* d_ws, size_t ws_size,
                              hipStream_t stream) {
  const float* x   = (const float*)d_in[0];
  const float* w1  = (const float*)d_in[1];
  const float* g1  = (const float*)d_in[2];
  const float* b1  = (const float*)d_in[3];
  const float* wca = (const float*)d_in[4];
  const float* wcb = (const float*)d_in[5];
  const float* wcc = (const float*)d_in[6];
  const float* wcd = (const float*)d_in[7];
  const float* w2  = (const float*)d_in[8];
  const float* g2  = (const float*)d_in[9];
  const float* b2  = (const float*)d_in[10];
  const float* w3  = (const float*)d_in[11];
  const float* g3  = (const float*)d_in[12];
  const float* b3  = (const float*)d_in[13];
  float* out = (float*)d_out;

  float* ws = (float*)d_ws;
  unsigned short* cat = (unsigned short*)(ws + 25165824);  // (n,HW,640) bf16
  unsigned short* y2b = (unsigned short*)(ws + 8388608);   // bf16 (n,HW,128)
  unsigned short* y3b = (unsigned short*)(ws + 25165824);  // overlay cat
  float* aux = ws + 46137344;
  unsigned short* w1b = (unsigned short*)(aux);
  unsigned short* w2b = (unsigned short*)(aux + 32768);
  unsigned short* w3b = (unsigned short*)(aux + 73728);
  unsigned short* wr  = (unsigned short*)(aux + 106496);
  float* part  = aux + 143360;                             // 65536 f
  float* part3 = aux + 208896;                             // 32768 f
  float* st1   = aux + 241664;
  float* st2   = aux + 241920;
  float* st3   = aux + 242176;

  dim3 blk(256);
  const int dynLds = 3 * DSLOTS * DP * 2 + 32 * 17 * 4;  // 47872 B
  (void)hipFuncSetAttribute((const void*)dynfused8_kernel,
                            hipFuncAttributeMaxDynamicSharedMemorySize, dynLds);

  prep_kernel<<<dim3(1120), blk, 0, stream>>>(w1, w2, w3, wca, wcb, wcc, wcd,
                                              w1b, w2b, w3b, wr);

  // stage 1: fused transpose+conv + GN1 partials -> cat 0..127 raw; stats; norm
  conv1f_kernel<<<dim3(256, 4), blk, 0, stream>>>(x, w1b, cat, part);
  gnf256_kernel<<<dim3(1), dim3(1024), 0, stream>>>(part, st1);
  gna_ip_kernel<<<dim3(8192), blk, 0, stream>>>(cat, st1, g1, b1, 640);

  // four fused dynamic branches -> cat cols 128..639 (bf16)
  dynfused8_kernel<<<dim3(512, 16), dim3(512), dynLds, stream>>>(cat, wr, cat);

  // stage 2: conv 640->128 (pipelined) + GN2 partials -> y2b raw; stats; norm
  conv_pm_kernel<640><<<dim3(256, 4), blk, 0, stream>>>(cat, w2b, y2b, part, 128);
  gnf256_kernel<<<dim3(1), dim3(1024), 0, stream>>>(part, st2);
  gna_ip_kernel<<<dim3(8192), blk, 0, stream>>>(y2b, st2, g2, b2, 128);

  // stage 3: conv 128->512 -> y3b bf16 + GN3 partials; stats; apply -> out
  conv3_kernel<<<dim3(128, 4, 4), blk, 0, stream>>>(y2b, w3b, y3b, part3);
  gnf3_kernel<<<dim3(1), dim3(1024), 0, stream>>>(part3, st3);
  gn3_apply_kernel<<<dim3(16384), blk, 0, stream>>>(y3b, st3, g3, b3, out);
}